// Round 9
// baseline (1943.886 us; speedup 1.0000x reference)
//
#include <hip/hip_runtime.h>

#define BB 256
#define TT 512
#define HH 512
#define NTH 512
#define SLOTG 65536   // granules per ping-pong slot (256 b x 256 kp)

typedef float    f32x4 __attribute__((ext_vector_type(4)));
typedef float    f32x2 __attribute__((ext_vector_type(2)));
typedef unsigned u32x4 __attribute__((ext_vector_type(4)));
typedef unsigned u32x2 __attribute__((ext_vector_type(2)));
typedef short    bf16x8 __attribute__((ext_vector_type(8)));

__device__ __forceinline__ f32x4 mfma16(u32x4 a, u32x4 b, f32x4 c) {
    return __builtin_amdgcn_mfma_f32_16x16x32_bf16(
        __builtin_bit_cast(bf16x8, a), __builtin_bit_cast(bf16x8, b), c, 0, 0, 0);
}

// MFMA RNN with bf16-split fp32 emulation (hi*hi + hi*lo + lo*hi).
// 32 groups x 8 WGs; group g owns batches 8g..8g+7; WG wj owns j-rows
// [64wj,+64). 8 waves = 4 m-tiles x 2 k-halves; A-frags (Wh hi/lo) live in
// the unified VGPR/AGPR file permanently (MFMA reads AGPRs directly -> no
// 128-VGPR wall). h exchanged as (bf16-pair,tag) 8B granules in d_ws
// ping-pong (R6 protocol), staged via LDS. 2 barriers/step.
__global__ void __attribute__((amdgpu_flat_work_group_size(NTH, NTH)))
rnn_mfma_kernel(const float* __restrict__ x,    // [B, T, 2]
                const float* __restrict__ Wh,   // [H, H]
                const float* __restrict__ Wx,   // [H, 2]
                float* __restrict__ out,        // [T+1, B, H]
                u32x2* __restrict__ gh,         // hi granules [2][256][256]
                u32x2* __restrict__ gl)         // lo granules [2][256][256]
{
    const int bid = blockIdx.x;
    const int tid = threadIdx.x;
    const int wj  = bid & 7;           // j-slice [64wj, +64)
    const int grp = bid >> 3;
    const int b0  = grp * 8;
    const int wid = tid >> 6, l = tid & 63;
    const int mv  = wid & 3, kh = wid >> 2;   // m-tile / k-half
    const int q   = l >> 4,  n  = l & 15;

    __shared__ unsigned SH[16 * 268];   // staged h hi-pairs [b][kp], stride 268
    __shared__ unsigned SL[16 * 268];   // staged h lo-pairs
    __shared__ float    pb[4][256];     // k-half partial C [mv][l*4]
    __shared__ float    xsh[8 * 1028];  // x stash [b][2t], stride 1028
    __shared__ float    ldspad[3200];   // pad LDS > 80KB -> 1 WG/CU (co-residency)
    ((volatile float*)ldspad)[tid] = 0.f;

    // ---- x stash (8 batches x 1024 floats) ----
    {
        const f32x4* xsrc = reinterpret_cast<const f32x4*>(x + (size_t)b0 * (TT * 2));
        #pragma unroll
        for (int i = 0; i < 4; ++i) {
            f32x4 v = xsrc[tid * 4 + i];
            int fo = tid * 16 + i * 4;
            *reinterpret_cast<f32x4*>(&xsh[(fo >> 10) * 1028 + (fo & 1023)]) = v;
        }
    }

    // ---- A-frags: Wh[j= 64wj+16mv+n][k = 256kh + 32kk + 8q + e] -> bf16 hi/lo ----
    u32x4 Ahi[8], Alo[8];
    {
        const float* wr = Wh + (size_t)(64 * wj + 16 * mv + n) * HH + kh * 256 + q * 8;
        #pragma unroll
        for (int kk = 0; kk < 8; ++kk) {
            const f32x4* p = reinterpret_cast<const f32x4*>(wr + kk * 32);
            f32x4 v0 = p[0], v1 = p[1];
            float f[8] = {v0[0], v0[1], v0[2], v0[3], v1[0], v1[1], v1[2], v1[3]};
            u32x4 hi, lo;
            #pragma unroll
            for (int r = 0; r < 4; ++r) {
                unsigned h0 = __builtin_bit_cast(unsigned, f[2*r]) >> 16;
                float hf0 = __builtin_bit_cast(float, h0 << 16);
                unsigned l0 = __builtin_bit_cast(unsigned, f[2*r] - hf0) >> 16;
                unsigned h1 = __builtin_bit_cast(unsigned, f[2*r+1]) >> 16;
                float hf1 = __builtin_bit_cast(float, h1 << 16);
                unsigned l1 = __builtin_bit_cast(unsigned, f[2*r+1] - hf1) >> 16;
                hi[r] = h0 | (h1 << 16);
                lo[r] = l0 | (l1 << 16);
            }
            Ahi[kk] = hi; Alo[kk] = lo;
        }
    }

    // ---- Wx for the 4 output rows this lane may publish ----
    const int j0 = 64 * wj + 16 * mv + 4 * q;
    float wxa[4], wxb[4];
    #pragma unroll
    for (int r = 0; r < 4; ++r) { wxa[r] = Wx[(j0+r)*2]; wxb[r] = Wx[(j0+r)*2 + 1]; }

    // ---- h0 granules (slot 0, tag 0) for own j-slice + out[0] ----
    {
        int bl = tid >> 6, idx = tid & 63;
        int kp = 32 * wj + (idx >> 1);
        unsigned data = (wj == 0 && idx == 0) ? 0x3F80u : 0u;  // bf16(1.0) at k=0, hi-plane
        u32x2 gr; gr.x = data; gr.y = 0u;
        u32x2* dst = ((idx & 1) ? gl : gh) + (size_t)(b0 + bl) * 256 + kp;
        asm volatile("global_store_dwordx2 %0, %1, off sc0 sc1" :: "v"(dst), "v"(gr) : "memory");
        out[(size_t)(b0 + bl) * HH + 64 * wj + idx] = (wj == 0 && idx == 0) ? 1.f : 0.f;
    }

    // ---- loader / consumer addressing ----
    const int bld = tid >> 6;               // loader batch-local (0..7)
    const int kp0 = (tid & 63) * 4;         // loader k-pair base
    const u32x2* ghb = gh + (size_t)(b0 + bld) * 256 + kp0;
    const u32x2* glb = gl + (size_t)(b0 + bld) * 256 + kp0;
    const int shw  = bld * 268 + kp0;       // stage write offset (u32)
    const int boff = n * 268 + kh * 128;    // B-frag row base (u32)

    for (int t = 0; t < TT; ++t) {
        const unsigned T = (unsigned)t;
        const u32x2* ah = ghb + (size_t)(t & 1) * SLOTG;
        const u32x2* al = glb + (size_t)(t & 1) * SLOTG;
        u32x4 hA, hB, lA, lB;
        asm volatile("global_load_dwordx4 %0, %4, off sc0 sc1\n\t"
                     "global_load_dwordx4 %1, %4, off offset:16 sc0 sc1\n\t"
                     "global_load_dwordx4 %2, %5, off sc0 sc1\n\t"
                     "global_load_dwordx4 %3, %5, off offset:16 sc0 sc1"
                     : "=&v"(hA), "=&v"(hB), "=&v"(lA), "=&v"(lB)
                     : "v"(ah), "v"(al) : "memory");
        for (;;) {
            asm volatile("s_waitcnt vmcnt(0)" ::: "memory");
            bool ok = (hA.y == T) & (hA.w == T) & (hB.y == T) & (hB.w == T) &
                      (lA.y == T) & (lA.w == T) & (lB.y == T) & (lB.w == T);
            if (__all(ok)) break;
            if (!ok) {
                asm volatile("global_load_dwordx4 %0, %4, off sc0 sc1\n\t"
                             "global_load_dwordx4 %1, %4, off offset:16 sc0 sc1\n\t"
                             "global_load_dwordx4 %2, %5, off sc0 sc1\n\t"
                             "global_load_dwordx4 %3, %5, off offset:16 sc0 sc1"
                             : "=&v"(hA), "=&v"(hB), "=&v"(lA), "=&v"(lB)
                             : "v"(ah), "v"(al) : "memory");
            }
        }
        {   // strip tags -> LDS planes
            u32x4 hv; hv[0] = hA.x; hv[1] = hA.z; hv[2] = hB.x; hv[3] = hB.z;
            u32x4 lv; lv[0] = lA.x; lv[1] = lA.z; lv[2] = lB.x; lv[3] = lB.z;
            *reinterpret_cast<u32x4*>(&SH[shw]) = hv;
            *reinterpret_cast<u32x4*>(&SL[shw]) = lv;
        }
        __syncthreads();   // B1: staged h ready

        // 24 MFMA: C[j][b] = sum_k (Whi+Wlo)(hhi+hlo), lo*lo dropped
        f32x4 C = {0.f, 0.f, 0.f, 0.f};
        #pragma unroll
        for (int kk = 0; kk < 8; ++kk) {
            int o = boff + kk * 16 + q * 4;
            u32x4 bh = *reinterpret_cast<const u32x4*>(&SH[o]);
            u32x4 bl2 = *reinterpret_cast<const u32x4*>(&SL[o]);
            C = mfma16(Ahi[kk], bh, C);
            C = mfma16(Ahi[kk], bl2, C);
            C = mfma16(Alo[kk], bh, C);
        }

        if (kh == 0)
            *reinterpret_cast<f32x4*>(&pb[mv][l * 4]) = C;
        __syncthreads();   // B2: partials ready
        if (kh == 1) {
            f32x4 p = *reinterpret_cast<const f32x4*>(&pb[mv][l * 4]);
            C += p;
            if (n < 8) {
                const int b = b0 + n;
                f32x2 xv = *reinterpret_cast<const f32x2*>(&xsh[n * 1028 + 2 * t]);
                float v[4]; unsigned hi16[4], lo16[4];
                #pragma unroll
                for (int r = 0; r < 4; ++r) {
                    float s = C[r] + wxa[r] * xv.x + wxb[r] * xv.y;
                    s = fmaxf(s, 0.f);
                    v[r] = s;
                    unsigned u = __builtin_bit_cast(unsigned, s);
                    hi16[r] = u >> 16;
                    float hf = __builtin_bit_cast(float, hi16[r] << 16);
                    lo16[r] = __builtin_bit_cast(unsigned, s - hf) >> 16;
                }
                const unsigned T1 = T + 1;
                u32x4 gH; gH[0] = hi16[0] | (hi16[1] << 16); gH[1] = T1;
                          gH[2] = hi16[2] | (hi16[3] << 16); gH[3] = T1;
                u32x4 gL; gL[0] = lo16[0] | (lo16[1] << 16); gL[1] = T1;
                          gL[2] = lo16[2] | (lo16[3] << 16); gL[3] = T1;
                size_t gi = (size_t)((t + 1) & 1) * SLOTG + (size_t)b * 256 + (j0 >> 1);
                u32x2* ph = gh + gi; u32x2* pl = gl + gi;
                asm volatile("global_store_dwordx4 %0, %2, off sc0 sc1\n\t"
                             "global_store_dwordx4 %1, %3, off sc0 sc1"
                             :: "v"(ph), "v"(pl), "v"(gH), "v"(gL) : "memory");
                *reinterpret_cast<f32x4*>(out + (size_t)(t + 1) * (BB * HH)
                                              + (size_t)b * HH + j0)
                    = f32x4{v[0], v[1], v[2], v[3]};
            }
        }
    }
}

extern "C" void kernel_launch(void* const* d_in, const int* in_sizes, int n_in,
                              void* d_out, int out_size, void* d_ws, size_t ws_size,
                              hipStream_t stream) {
    const float* x  = (const float*)d_in[0];
    const float* Wh = (const float*)d_in[1];
    const float* Wx = (const float*)d_in[2];
    float* out = (float*)d_out;
    u32x2* gh = (u32x2*)d_ws;                       // 1 MB
    u32x2* gl = (u32x2*)((char*)d_ws + (1 << 20));  // 1 MB
    rnn_mfma_kernel<<<BB, NTH, 0, stream>>>(x, Wh, Wx, out, gh, gl);
}

// Round 10
// 1472.146 us; speedup vs baseline: 1.3204x; 1.3204x over previous
//
#include <hip/hip_runtime.h>

#define BB 256
#define TT 512
#define HH 512
#define NTH 256
#define SLOTP 65536   // u32x4 pair-granules per ping-pong slot (256 b x 256 kp)

typedef float    f32x4 __attribute__((ext_vector_type(4)));
typedef float    f32x2 __attribute__((ext_vector_type(2)));
typedef unsigned u32x4 __attribute__((ext_vector_type(4)));
typedef unsigned u32x2 __attribute__((ext_vector_type(2)));
typedef short    bf16x8 __attribute__((ext_vector_type(8)));

__device__ __forceinline__ f32x4 mfma16(u32x4 a, u32x4 b, f32x4 c) {
    return __builtin_amdgcn_mfma_f32_16x16x32_bf16(
        __builtin_bit_cast(bf16x8, a), __builtin_bit_cast(bf16x8, b), c, 0, 0, 0);
}
// round-to-nearest-even bf16 (upper 16 bits)
__device__ __forceinline__ unsigned rne16(float f) {
    unsigned u = __builtin_bit_cast(unsigned, f);
    return (u + 0x7FFFu + ((u >> 16) & 1u)) >> 16;
}

// Quad-split MFMA RNN, bf16-split fp32 emulation (hi*hi + hi*lo + lo*hi).
// 64 groups x 4 WGs; WG q owns j-rows [128q,+128) for batches 4g..4g+3.
// 256 threads = 4 waves (1/SIMD); A-frags (256 u32/thread, rotation-indexed
// so all reg-array indices are static) live in the unified VGPR/AGPR file.
// h exchanged as 16B self-tagged k-pair granules (hi|hi, lo|lo, tag, tag)
// in d_ws ping-pong, sc0sc1 (L3-coherent); own quarter staged locally.
// B-frags staged fragment-linear in LDS -> ds_read_b128 at l*16B, conflict-free.
__global__ void __attribute__((amdgpu_flat_work_group_size(NTH, NTH)))
__attribute__((amdgpu_waves_per_eu(1, 1)))
rnn_mfma4(const float* __restrict__ x,    // [B, T, 2]
          const float* __restrict__ Wh,   // [H, H]
          const float* __restrict__ Wx,   // [H, 2]
          float* __restrict__ out,        // [T+1, B, H]
          u32x4* __restrict__ xch)        // [2][256][256] pair granules (4 MB)
{
    const int bid = blockIdx.x;
    const int tid = threadIdx.x;
    const int q   = bid & 3;               // owned j-quarter
    const int b0  = (bid >> 2) * 4;        // 4 batches per group
    const int w   = tid >> 6, l = tid & 63;
    const int col = l & 15, qr = l >> 4;
    const int J0  = 128 * q;

    __shared__ unsigned SH[2][16][256];    // hi-plane B tiles, frag-linear (32 KB)
    __shared__ unsigned SL[2][16][256];    // lo-plane (32 KB)
    __shared__ float    xsb[4][1024];      // x stash (16 KB)
    __shared__ unsigned ldspad[512];       // push LDS > 80 KB -> 1 WG/CU
    ((volatile unsigned*)ldspad)[tid & 511] = 0u;

    // ---- x stash: 4 batches x 1024 floats ----
    #pragma unroll
    for (int it = 0; it < 4; ++it) {
        int idx = tid + it * 256;
        f32x4 v = reinterpret_cast<const f32x4*>(x + (size_t)b0 * (TT * 2))[idx];
        *reinterpret_cast<f32x4*>(&xsb[idx >> 8][(idx & 255) * 4]) = v;
    }

    // ---- A-frags, rotation-indexed: frag fk <-> global k-block (4q+fk)&15 ----
    u32x4 Ahi[2][16], Alo[2][16];
    #pragma unroll
    for (int i = 0; i < 2; ++i) {
        const float* rp = Wh + (size_t)(J0 + (2 * w + i) * 16 + col) * HH + qr * 8;
        #pragma unroll
        for (int fk = 0; fk < 16; ++fk) {
            int kb = (4 * q + fk) & 15;
            const f32x4* p = reinterpret_cast<const f32x4*>(rp + kb * 32);
            f32x4 v0 = p[0], v1 = p[1];
            float f[8] = {v0[0], v0[1], v0[2], v0[3], v1[0], v1[1], v1[2], v1[3]};
            u32x4 hi, lo;
            #pragma unroll
            for (int r = 0; r < 4; ++r) {
                unsigned h0 = rne16(f[2*r]);
                unsigned l0 = rne16(f[2*r]   - __builtin_bit_cast(float, h0 << 16));
                unsigned h1 = rne16(f[2*r+1]);
                unsigned l1 = rne16(f[2*r+1] - __builtin_bit_cast(float, h1 << 16));
                hi[r] = h0 | (h1 << 16);
                lo[r] = l0 | (l1 << 16);
            }
            Ahi[i][fk] = hi; Alo[i][fk] = lo;
        }
    }

    // ---- Wx coefficients for the rows this lane may publish ----
    float wxA[2][4], wxB[2][4];
    #pragma unroll
    for (int i = 0; i < 2; ++i)
        #pragma unroll
        for (int r = 0; r < 4; ++r) {
            int j = J0 + (2 * w + i) * 16 + qr * 4 + r;
            wxA[i][r] = Wx[j * 2]; wxB[i][r] = Wx[j * 2 + 1];
        }

    // ---- zero both staging buffers (cols>=4 stay 0 forever -> clean MFMA) ----
    {
        u32x4 zz = {0u, 0u, 0u, 0u};
        #pragma unroll
        for (int it = 0; it < 8; ++it) reinterpret_cast<u32x4*>(SH)[tid + it * 256] = zz;
        #pragma unroll
        for (int it = 0; it < 8; ++it) reinterpret_cast<u32x4*>(SL)[tid + it * 256] = zz;
    }
    // ---- out[0] ----
    {
        int lin = tid * 2, b = lin >> 7, jl = lin & 127;
        f32x2 v; v[0] = (J0 + jl == 0) ? 1.f : 0.f; v[1] = 0.f;
        *reinterpret_cast<f32x2*>(out + (size_t)(b0 + b) * HH + J0 + jl) = v;
    }
    __syncthreads();
    if (tid < 4) SH[0][0][4 * tid] = 0x3F80u;   // h0[k=0]=1.0 (bf16), all 4 batches
    __syncthreads();

    // ---- remote granule assignment: 3 per thread, bank-spread permutation ----
    int gbase[3], gkb[3], gd[3];
    #pragma unroll
    for (int j = 0; j < 3; ++j) {
        int perm = ((tid & 3) << 6) | (tid >> 2);    // b = tid&3, m = tid>>2
        int b = (perm >> 6) & 3, m = perm & 63;
        int Q = (q + j + 1) & 3;
        gbase[j] = (b0 + b) * 256 + Q * 64 + m;      // pair index in slot
        gkb[j]   = Q * 4 + (m >> 4);
        gd[j]    = (((m & 15) >> 2) * 16 + b) * 4 + (m & 3);
    }

    const size_t ostep = (size_t)BB * HH;

    for (int t = 0; t < TT; ++t) {
        const int s = t & 1, s1 = s ^ 1;
        const unsigned T = (unsigned)t;
        u32x4 g0, g1, g2;
        const u32x4* a0 = xch + (size_t)s * SLOTP + gbase[0];
        const u32x4* a1 = xch + (size_t)s * SLOTP + gbase[1];
        const u32x4* a2 = xch + (size_t)s * SLOTP + gbase[2];
        if (t > 0) {
            asm volatile("global_load_dwordx4 %0, %3, off sc0 sc1\n\t"
                         "global_load_dwordx4 %1, %4, off sc0 sc1\n\t"
                         "global_load_dwordx4 %2, %5, off sc0 sc1"
                         : "=&v"(g0), "=&v"(g1), "=&v"(g2)
                         : "v"(a0), "v"(a1), "v"(a2) : "memory");
        }

        // phase 1: own quarter (fk 0..3) -- hides the L3 round trip
        f32x4 C0 = {0.f, 0.f, 0.f, 0.f}, C1 = {0.f, 0.f, 0.f, 0.f};
        #pragma unroll
        for (int fk = 0; fk < 4; ++fk) {
            int kb = (4 * q + fk) & 15;
            u32x4 bh = *reinterpret_cast<const u32x4*>(&SH[s][kb][l * 4]);
            u32x4 bl = *reinterpret_cast<const u32x4*>(&SL[s][kb][l * 4]);
            C0 = mfma16(Ahi[0][fk], bh, C0);
            C0 = mfma16(Ahi[0][fk], bl, C0);
            C0 = mfma16(Alo[0][fk], bh, C0);
            C1 = mfma16(Ahi[1][fk], bh, C1);
            C1 = mfma16(Ahi[1][fk], bl, C1);
            C1 = mfma16(Alo[1][fk], bh, C1);
        }

        // spin until all 3 granules carry tag t, then land into LDS
        if (t > 0) {
            for (;;) {
                asm volatile("s_waitcnt vmcnt(0)" ::: "memory");
                bool ok = (g0.z == T) & (g0.w == T) & (g1.z == T) & (g1.w == T) &
                          (g2.z == T) & (g2.w == T);
                if (__all(ok)) break;
                asm volatile("global_load_dwordx4 %0, %3, off sc0 sc1\n\t"
                             "global_load_dwordx4 %1, %4, off sc0 sc1\n\t"
                             "global_load_dwordx4 %2, %5, off sc0 sc1"
                             : "=&v"(g0), "=&v"(g1), "=&v"(g2)
                             : "v"(a0), "v"(a1), "v"(a2) : "memory");
            }
            SH[s][gkb[0]][gd[0]] = g0.x;  SL[s][gkb[0]][gd[0]] = g0.y;
            SH[s][gkb[1]][gd[1]] = g1.x;  SL[s][gkb[1]][gd[1]] = g1.y;
            SH[s][gkb[2]][gd[2]] = g2.x;  SL[s][gkb[2]][gd[2]] = g2.y;
        }
        __syncthreads();   // B1: full h(t) staged

        // phase 2: remote three quarters (fk 4..15)
        #pragma unroll
        for (int fk = 4; fk < 16; ++fk) {
            int kb = (4 * q + fk) & 15;
            u32x4 bh = *reinterpret_cast<const u32x4*>(&SH[s][kb][l * 4]);
            u32x4 bl = *reinterpret_cast<const u32x4*>(&SL[s][kb][l * 4]);
            C0 = mfma16(Ahi[0][fk], bh, C0);
            C0 = mfma16(Ahi[0][fk], bl, C0);
            C0 = mfma16(Alo[0][fk], bh, C0);
            C1 = mfma16(Ahi[1][fk], bh, C1);
            C1 = mfma16(Ahi[1][fk], bl, C1);
            C1 = mfma16(Alo[1][fk], bh, C1);
        }

        // epilogue: x-projection + ReLU; publish global + stage own locally
        if (col < 4) {
            f32x2 xv = *reinterpret_cast<const f32x2*>(&xsb[col][2 * t]);
            const unsigned T1 = T + 1u;
            #pragma unroll
            for (int i = 0; i < 2; ++i) {
                f32x4 Cv = i ? C1 : C0;
                f32x4 v;
                #pragma unroll
                for (int r = 0; r < 4; ++r)
                    v[r] = fmaxf(Cv[r] + wxA[i][r] * xv[0] + wxB[i][r] * xv[1], 0.f);
                unsigned hi[4], lo[4];
                #pragma unroll
                for (int r = 0; r < 4; ++r) {
                    hi[r] = rne16(v[r]);
                    lo[r] = rne16(v[r] - __builtin_bit_cast(float, hi[r] << 16));
                }
                unsigned H0 = hi[0] | (hi[1] << 16), L0 = lo[0] | (lo[1] << 16);
                unsigned H1 = hi[2] | (hi[3] << 16), L1 = lo[2] | (lo[3] << 16);
                int j0 = J0 + (2 * w + i) * 16 + qr * 4;
                u32x4 ga = {H0, L0, T1, T1}, gb = {H1, L1, T1, T1};
                u32x4* pd = xch + (size_t)s1 * SLOTP + (size_t)(b0 + col) * 256 + (j0 >> 1);
                asm volatile("global_store_dwordx4 %0, %2, off sc0 sc1\n\t"
                             "global_store_dwordx4 %1, %3, off sc0 sc1"
                             :: "v"(pd), "v"(pd + 1), "v"(ga), "v"(gb) : "memory");
                int kbn = j0 >> 5;
                int d0 = (((j0 & 31) >> 3) * 16 + col) * 4 + ((j0 & 4) >> 1);
                *reinterpret_cast<u32x2*>(&SH[s1][kbn][d0]) = u32x2{H0, H1};
                *reinterpret_cast<u32x2*>(&SL[s1][kbn][d0]) = u32x2{L0, L1};
                *reinterpret_cast<f32x4*>(out + (size_t)(t + 1) * ostep
                                              + (size_t)(b0 + col) * HH + j0) = v;
            }
        }
        __syncthreads();   // B2: own-quarter of buffer s1 staged for next step
    }
}

extern "C" void kernel_launch(void* const* d_in, const int* in_sizes, int n_in,
                              void* d_out, int out_size, void* d_ws, size_t ws_size,
                              hipStream_t stream) {
    const float* x  = (const float*)d_in[0];
    const float* Wh = (const float*)d_in[1];
    const float* Wx = (const float*)d_in[2];
    float* out = (float*)d_out;
    u32x4* xch = (u32x4*)d_ws;    // needs 2*256*256*16 = 4 MB of workspace
    rnn_mfma4<<<BB, NTH, 0, stream>>>(x, Wh, Wx, out, xch);
}